// Round 13
// baseline (176.378 us; speedup 1.0000x reference)
//
#include <hip/hip_runtime.h>
#include <math.h>
#include <stddef.h>

#define N224 224
#define PIX 50176      // 224*224
#define ROWS113 25312  // 113*224, Cx/Sx rows per image

// ---- ws float offsets ----
#define OFF_SX    1214976
#define OFF_SPEC  4816896
#define OFF_WT    3211264              // right after h1 (16*16*112*112)
#define OFF_WT2   (OFF_WT + 24576)    // wt3v = 32*64*12
#define OFF_WT1   (OFF_WT + 30720)    // wt2v = 16*32*12
#define OFF_SU3   (OFF_WT + 31296)    // wt1v = 3*16*12
#define OFF_SU2   (OFF_WT + 31424)    // su3 = 128
#define OFF_SU1   (OFF_WT + 31488)    // su2 = 64
#define OFF_PART  (OFF_WT + 32768)    // 16*64*224 = 229376 floats

// ---------------- prep: weight transpose (vectorized layout) + BN fold ------
__global__ __launch_bounds__(256) void prep(
    const float* __restrict__ c1w, const float* __restrict__ c2w,
    const float* __restrict__ c3w, const float* __restrict__ c1b,
    const float* __restrict__ c2b, const float* __restrict__ c3b,
    const float* __restrict__ g1, const float* __restrict__ be1,
    const float* __restrict__ m1, const float* __restrict__ v1,
    const float* __restrict__ g2, const float* __restrict__ be2,
    const float* __restrict__ m2, const float* __restrict__ v2,
    const float* __restrict__ g3, const float* __restrict__ be3,
    const float* __restrict__ m3, const float* __restrict__ v3,
    float* __restrict__ wt3, float* __restrict__ wt2, float* __restrict__ wt1,
    float* __restrict__ su3, float* __restrict__ su2, float* __restrict__ su1)
{
  const int idx = blockIdx.x * 256 + threadIdx.x;
  const int stride = gridDim.x * 256;
  for (int i = idx; i < 32*64*12; i += stride) {       // wt3v[cc*768+co*12+k]
    const int cc = i / 768, r = i % 768, co = r / 12, k = r % 12;
    wt3[i] = (k < 9) ? c3w[co*288 + cc*9 + k] : 0.f;
  }
  for (int i = idx; i < 16*32*12; i += stride) {       // wt2v[cc*384+co*12+k]
    const int cc = i / 384, r = i % 384, co = r / 12, k = r % 12;
    wt2[i] = (k < 9) ? c2w[co*144 + cc*9 + k] : 0.f;
  }
  for (int i = idx; i < 3*16*12; i += stride) {        // wt1v[cc*192+co*12+k]
    const int cc = i / 192, r = i % 192, co = r / 12, k = r % 12;
    wt1[i] = (k < 9) ? c1w[co*27 + cc*9 + k] : 0.f;
  }
  if (idx < 64) {
    const float s = g3[idx] * rsqrtf(v3[idx] + 1e-5f);
    su3[idx] = s; su3[64+idx] = (c3b[idx] - m3[idx]) * s + be3[idx];
  } else if (idx < 96) {
    const int c = idx - 64;
    const float s = g2[c] * rsqrtf(v2[c] + 1e-5f);
    su2[c] = s; su2[32+c] = (c2b[c] - m2[c]) * s + be2[c];
  } else if (idx < 112) {
    const int c = idx - 96;
    const float s = g1[c] * rsqrtf(v1[c] + 1e-5f);
    su1[c] = s; su1[16+c] = (c1b[c] - m1[c]) * s + be1[c];
  }
}

// ---------------- DFT stage 1 (half rows): Cx = C @ x, Sx = S @ x -----------
__global__ __launch_bounds__(256) void dft1(
    const float* __restrict__ seq, const float* __restrict__ Cm,
    const float* __restrict__ Sm, float* __restrict__ Cx, float* __restrict__ Sx)
{
  const int p = blockIdx.z;
  const int b = p / 3, ch = p % 3;
  const float* __restrict__ x = seq + ((((size_t)b * 8 + 4) * 3 + ch) * PIX);
  const int i0 = blockIdx.y * 32;
  const int k0 = blockIdx.x * 32;
  const int tid = threadIdx.x;
  const int tx = tid & 15, ty = tid >> 4;
  __shared__ float Ctt[16][36], Stt[16][36], Xt[16][36];
  float aC[2][2] = {{0,0},{0,0}}, aS[2][2] = {{0,0},{0,0}};

  const int sidx = tid & 127;
  const int srow = sidx >> 2;
  const int skq  = (sidx & 3) * 4;
  const bool isC = tid < 128;
  const float* __restrict__ csb = (isC ? Cm : Sm) + (size_t)(i0 + srow) * N224 + skq;
  const int xjr = tid >> 4;
  const int xc  = (tid & 15) * 2;
  const float* __restrict__ xb = x + (size_t)xjr * N224 + k0 + xc;

  for (int jt = 0; jt < 14; ++jt) {
    const int j = jt * 16;
    __syncthreads();
    {
      const float4 v = *(const float4*)(csb + j);
      float (*dst)[36] = isC ? Ctt : Stt;
      dst[skq+0][srow] = v.x; dst[skq+1][srow] = v.y;
      dst[skq+2][srow] = v.z; dst[skq+3][srow] = v.w;
      *(float2*)&Xt[xjr][xc] = *(const float2*)(xb + (size_t)j * N224);
    }
    __syncthreads();
#pragma unroll
    for (int jj = 0; jj < 16; ++jj) {
      const float2 cv = *(const float2*)&Ctt[jj][2*ty];
      const float2 sv = *(const float2*)&Stt[jj][2*ty];
      const float2 xv = *(const float2*)&Xt[jj][2*tx];
      aC[0][0] = fmaf(cv.x, xv.x, aC[0][0]); aC[0][1] = fmaf(cv.x, xv.y, aC[0][1]);
      aC[1][0] = fmaf(cv.y, xv.x, aC[1][0]); aC[1][1] = fmaf(cv.y, xv.y, aC[1][1]);
      aS[0][0] = fmaf(sv.x, xv.x, aS[0][0]); aS[0][1] = fmaf(sv.x, xv.y, aS[0][1]);
      aS[1][0] = fmaf(sv.y, xv.x, aS[1][0]); aS[1][1] = fmaf(sv.y, xv.y, aS[1][1]);
    }
  }
  const size_t b113 = (size_t)p * ROWS113;
#pragma unroll
  for (int a = 0; a < 2; ++a) {
    const int i = i0 + 2*ty + a;
    if (i <= 112) {
      const size_t off = b113 + (size_t)i * N224 + k0 + 2*tx;
      *(float2*)&Cx[off] = make_float2(aC[a][0], aC[a][1]);
      *(float2*)&Sx[off] = make_float2(aS[a][0], aS[a][1]);
    }
  }
}

// --------- DFT stage 2 (QUARTER grid): log|X| + fftshift, 4-way mirror ------
__global__ __launch_bounds__(256) void dft2(
    const float* __restrict__ Cx, const float* __restrict__ Sx,
    const float* __restrict__ Cm, const float* __restrict__ Sm,
    float* __restrict__ spec)
{
  const int p = blockIdx.z;
  const int i0 = blockIdx.y * 32;
  const int k0 = blockIdx.x * 32;
  const int tid = threadIdx.x;
  const int tx = tid & 15, ty = tid >> 4;
  const size_t b113 = (size_t)p * ROWS113;
  __shared__ float CxT[16][36], SxT[16][36], Ct[16][36], St[16][36];
  float p1[2][2] = {{0,0},{0,0}}, p2[2][2] = {{0,0},{0,0}};
  float p3[2][2] = {{0,0},{0,0}}, p4[2][2] = {{0,0},{0,0}};

  const int sidx = tid & 127;
  const int srow = sidx >> 2;
  const int skq  = (sidx & 3) * 4;
  const bool isCx = tid < 128;
  const int ri = (i0 + srow > 112) ? 112 : i0 + srow;
  const float* __restrict__ ab = (isCx ? Cx : Sx) + b113 + (size_t)ri * N224 + skq;
  const int jr = tid >> 4;
  const int cc2 = (tid & 15) * 2;
  const float* __restrict__ cb = Cm + (size_t)jr * N224 + k0 + cc2;
  const float* __restrict__ sb2 = Sm + (size_t)jr * N224 + k0 + cc2;

  for (int jt = 0; jt < 14; ++jt) {
    const int j = jt * 16;
    __syncthreads();
    {
      const float4 v = *(const float4*)(ab + j);
      float (*dst)[36] = isCx ? CxT : SxT;
      dst[skq+0][srow] = v.x; dst[skq+1][srow] = v.y;
      dst[skq+2][srow] = v.z; dst[skq+3][srow] = v.w;
      *(float2*)&Ct[jr][cc2] = *(const float2*)(cb + (size_t)j * N224);
      *(float2*)&St[jr][cc2] = *(const float2*)(sb2 + (size_t)j * N224);
    }
    __syncthreads();
#pragma unroll
    for (int jj = 0; jj < 16; ++jj) {
      const float2 cxv = *(const float2*)&CxT[jj][2*ty];
      const float2 sxv = *(const float2*)&SxT[jj][2*ty];
      const float2 ccv = *(const float2*)&Ct[jj][2*tx];
      const float2 ssv = *(const float2*)&St[jj][2*tx];
      const float cxa[2] = {cxv.x, cxv.y};
      const float sxa[2] = {sxv.x, sxv.y};
      const float cca[2] = {ccv.x, ccv.y};
      const float ssa[2] = {ssv.x, ssv.y};
#pragma unroll
      for (int a = 0; a < 2; ++a)
#pragma unroll
        for (int d = 0; d < 2; ++d) {
          p1[a][d] = fmaf(cxa[a], cca[d], p1[a][d]);
          p2[a][d] = fmaf(sxa[a], ssa[d], p2[a][d]);
          p3[a][d] = fmaf(cxa[a], ssa[d], p3[a][d]);
          p4[a][d] = fmaf(sxa[a], cca[d], p4[a][d]);
        }
    }
  }
  const size_t sb = (size_t)p * PIX;
#pragma unroll
  for (int a = 0; a < 2; ++a) {
    const int i = i0 + 2*ty + a;
    if (i > 112) continue;
    const int shi  = (i < 112) ? i + 112 : i - 112;
    const int shmi = 112 - i;
    const bool irm = (i >= 1) && (i <= 111);
#pragma unroll
    for (int d = 0; d < 2; ++d) {
      const int k = k0 + 2*tx + d;
      if (k > 112) continue;
      const float r1 = p1[a][d] - p2[a][d];
      const float i1 = p3[a][d] + p4[a][d];
      const float sp1v = logf(sqrtf(fmaf(r1, r1, fmaf(i1, i1, 1e-8f))) + 1e-8f);
      const float r2v = p1[a][d] + p2[a][d];
      const float i2v = p3[a][d] - p4[a][d];
      const float sp2v = logf(sqrtf(fmaf(r2v, r2v, fmaf(i2v, i2v, 1e-8f))) + 1e-8f);
      const int shk  = (k < 112) ? k + 112 : k - 112;
      const int shmk = 112 - k;
      const bool krm = (k >= 1) && (k <= 111);
      spec[sb + (size_t)shi*N224 + shk] = sp1v;
      if (irm)        spec[sb + (size_t)shmi*N224 + shk ] = sp2v;
      if (krm)        spec[sb + (size_t)shi *N224 + shmk] = sp2v;
      if (irm && krm) spec[sb + (size_t)shmi*N224 + shmk] = sp1v;
    }
  }
}

// -------- conv1 (3->16)+BN+ReLU+pool: lane-cr split, shfl pool --------------
__global__ __launch_bounds__(256) void conv1(
    const float* __restrict__ spec, const float* __restrict__ wt1,
    const float* __restrict__ su1, float* __restrict__ out)
{
  const int band = blockIdx.x, b = blockIdx.y;
  const int tid = threadIdx.x;
  const int lane = tid & 63, w = tid >> 6;
  const int co = lane & 15, cr = (lane >> 4) & 1, xs = lane >> 5;
  const int xh = w >> 1, xq = w & 1;
  __shared__ float in_t[3][4][232];
  for (int i = tid; i < 3*4*232; i += 256) {
    const int c = i % 232, r = (i / 232) % 4, cc = i / 928;
    const int y = band*2 - 1 + r, gx = c - 1;
    float v = 0.f;
    if (c < 226 && y >= 0 && y < 224 && gx >= 0 && gx < 224)
      v = spec[((size_t)b*3 + cc) * PIX + (size_t)y * N224 + gx];
    in_t[cc][r][c] = v;
  }
  __syncthreads();
  const int X0 = xh*112 + xq*56 + xs*28;
  float acc[28];
#pragma unroll
  for (int px = 0; px < 28; ++px) acc[px] = 0.f;
#pragma unroll
  for (int cc = 0; cc < 3; ++cc) {
    const float4 w0 = *(const float4*)&wt1[cc*192 + co*12];
    const float4 w1 = *(const float4*)&wt1[cc*192 + co*12 + 4];
    const float  w8 = wt1[cc*192 + co*12 + 8];
    const float wr[9] = {w0.x, w0.y, w0.z, w0.w, w1.x, w1.y, w1.z, w1.w, w8};
#pragma unroll
    for (int ky = 0; ky < 3; ++ky) {
      float xr[32];
      const float4* rp = (const float4*)&in_t[cc][cr + ky][X0];
#pragma unroll
      for (int t = 0; t < 8; ++t) {
        const float4 v = rp[t];
        xr[4*t]=v.x; xr[4*t+1]=v.y; xr[4*t+2]=v.z; xr[4*t+3]=v.w;
      }
#pragma unroll
      for (int px = 0; px < 28; ++px) {
        acc[px] = fmaf(xr[px  ], wr[ky*3  ], acc[px]);
        acc[px] = fmaf(xr[px+1], wr[ky*3+1], acc[px]);
        acc[px] = fmaf(xr[px+2], wr[ky*3+2], acc[px]);
      }
    }
  }
  const float s = su1[co], u = su1[16+co];
  float m[14];
#pragma unroll
  for (int p = 0; p < 14; ++p)
    m[p] = fmaxf(acc[2*p]*s + u, acc[2*p+1]*s + u);
#pragma unroll
  for (int p = 0; p < 14; ++p) {
    const float pm = __shfl_xor(m[p], 16);
    m[p] = fmaxf(fmaxf(m[p], pm), 0.f);
  }
  if (cr == 0) {
    const int pxb = X0 >> 1;
    float* op = &out[(((size_t)b*16 + co)*112 + band)*112 + pxb];
#pragma unroll
    for (int p = 0; p < 14; ++p) op[p] = m[p];
  }
}

// -------- conv2 (16->32)+BN+ReLU+pool: cr-split -----------------------------
__global__ __launch_bounds__(256) void conv2(
    const float* __restrict__ h1, const float* __restrict__ wt2,
    const float* __restrict__ su2, float* __restrict__ out)
{
  const int xh = blockIdx.x, band = blockIdx.y, b = blockIdx.z;
  const int tid = threadIdx.x;
  const int lane = tid & 63, w = tid >> 6;
  const int co = lane & 31, cr = lane >> 5;
  __shared__ float in_t[16][4][64];
  for (int i = tid; i < 16*4*58; i += 256) {
    const int c = i % 58, r = (i / 58) % 4, cc = i / 232;
    const int y = band*2 - 1 + r, gx = xh*56 - 1 + c;
    float v = 0.f;
    if (y >= 0 && y < 112 && gx >= 0 && gx < 112)
      v = h1[(((size_t)b*16 + cc)*112 + y)*112 + gx];
    in_t[cc][r][c] = v;
  }
  __syncthreads();
  const int X0 = w * 14;                   // 0,14,28,42 — 8B-aligned
  float acc[14];
#pragma unroll
  for (int px = 0; px < 14; ++px) acc[px] = 0.f;
  const float* __restrict__ wp = wt2 + co*12;
  float4 nw0 = *(const float4*)(wp);
  float4 nw1 = *(const float4*)(wp + 4);
  float  nw8 = wp[8];
  for (int cc = 0; cc < 16; ++cc) {
    const float4 w0 = nw0, w1 = nw1; const float w8 = nw8;
    if (cc < 15) {
      const float* np = wp + (cc + 1) * 384;
      nw0 = *(const float4*)(np);
      nw1 = *(const float4*)(np + 4);
      nw8 = np[8];
    }
    const float wr[9] = {w0.x, w0.y, w0.z, w0.w, w1.x, w1.y, w1.z, w1.w, w8};
    float xr[3][16];
#pragma unroll
    for (int ky = 0; ky < 3; ++ky) {
      const float2* rp = (const float2*)&in_t[cc][cr + ky][X0];
#pragma unroll
      for (int t = 0; t < 8; ++t) {
        const float2 v = rp[t];
        xr[ky][2*t] = v.x; xr[ky][2*t+1] = v.y;
      }
    }
#pragma unroll
    for (int ky = 0; ky < 3; ++ky)
#pragma unroll
      for (int px = 0; px < 14; ++px) {
        acc[px] = fmaf(xr[ky][px  ], wr[ky*3  ], acc[px]);
        acc[px] = fmaf(xr[ky][px+1], wr[ky*3+1], acc[px]);
        acc[px] = fmaf(xr[ky][px+2], wr[ky*3+2], acc[px]);
      }
  }
  const float s = su2[co], u = su2[32+co];
  float m[7];
#pragma unroll
  for (int p = 0; p < 7; ++p)
    m[p] = fmaxf(acc[2*p]*s + u, acc[2*p+1]*s + u);
#pragma unroll
  for (int p = 0; p < 7; ++p) {
    const float pm = __shfl_xor(m[p], 32);
    m[p] = fmaxf(fmaxf(m[p], pm), 0.f);
  }
  if (cr == 0) {
    float* op = &out[(((size_t)b*32 + co)*56 + band)*56 + xh*28 + w*7];
#pragma unroll
    for (int p = 0; p < 7; ++p) op[p] = m[p];
  }
}

// -------- conv3 (32->64)+BN+ReLU+partial mean: cc-SPLIT x4 for occupancy ----
// grid (4 ccq, 56 row, 16 b) = 3584 blocks (14 blocks/CU, wave-capped at 8).
// Each block: 8 input channels ccq*8..+7. 256 thr = 64 co x 4 x-slices of 14.
// Inner loop identical to r11 (float2 reads, xr upfront).
__global__ __launch_bounds__(256) void conv3(
    const float* __restrict__ h2, const float* __restrict__ wt3,
    const float* __restrict__ su3, float* __restrict__ part)
{
  const int ccq = blockIdx.x, band = blockIdx.y, b = blockIdx.z;
  const int tid = threadIdx.x;
  const int co = tid & 63, w = tid >> 6;
  __shared__ float in_t[8][3][64];
  __shared__ float red[4][64];
  for (int i = tid; i < 8*3*58; i += 256) {
    const int c = i % 58, r = (i / 58) % 3, ccl = i / 174;
    const int y = band - 1 + r, gx = c - 1;
    float v = 0.f;
    if (y >= 0 && y < 56 && gx >= 0 && gx < 56)
      v = h2[(((size_t)b*32 + ccq*8 + ccl)*56 + y)*56 + gx];
    in_t[ccl][r][c] = v;
  }
  __syncthreads();
  const int X0 = w * 14;
  float acc[14];
#pragma unroll
  for (int px = 0; px < 14; ++px) acc[px] = 0.f;
  const float* __restrict__ wp = wt3 + (size_t)ccq*8*768 + co*12;
  float4 nw0 = *(const float4*)(wp);
  float4 nw1 = *(const float4*)(wp + 4);
  float  nw8 = wp[8];
  for (int cc = 0; cc < 8; ++cc) {
    const float4 w0 = nw0, w1 = nw1; const float w8 = nw8;
    if (cc < 7) {
      const float* np = wp + (cc + 1) * 768;
      nw0 = *(const float4*)(np);
      nw1 = *(const float4*)(np + 4);
      nw8 = np[8];
    }
    const float wr[9] = {w0.x, w0.y, w0.z, w0.w, w1.x, w1.y, w1.z, w1.w, w8};
    float xr[3][16];
#pragma unroll
    for (int rr = 0; rr < 3; ++rr) {
      const float2* rp = (const float2*)&in_t[cc][rr][X0];
#pragma unroll
      for (int t = 0; t < 8; ++t) {
        const float2 v = rp[t];
        xr[rr][2*t] = v.x; xr[rr][2*t+1] = v.y;
      }
    }
#pragma unroll
    for (int rr = 0; rr < 3; ++rr)
#pragma unroll
      for (int px = 0; px < 14; ++px) {
        acc[px] = fmaf(xr[rr][px  ], wr[rr*3  ], acc[px]);
        acc[px] = fmaf(xr[rr][px+1], wr[rr*3+1], acc[px]);
        acc[px] = fmaf(xr[rr][px+2], wr[rr*3+2], acc[px]);
      }
  }
  // NOTE: BN+ReLU can only be applied AFTER summing all 32 channels.
  // Partial blocks hold raw conv partial sums; ccq==0 block also must not
  // apply ReLU. So: store raw px-sums per ccq; finish kernel applies BN+ReLU
  // per-pixel? -> NOT possible after px-reduction. Instead: reduce px AFTER
  // full-channel sum requires pixel-level partials. To keep the px reduction
  // here, we store the 14-px raw sums reduced? ReLU is pointwise per pixel,
  // so we must NOT reduce px before BN+ReLU unless all channels are in.
  // Solution: each block stores sum over its px-slice of the PARTIAL conv —
  // but ReLU(a+b) != ReLU(a)+ReLU(b). Hence we store per-(ccq) raw pixel
  // partial SUMS only after... we cannot. Therefore: store raw per-px
  // partials to part2 and let a finish kernel add 4 quarters, BN+ReLU, and
  // reduce. part2 layout: [(b*64+co)][ccq][56 band][56 px] too big (12.8M).
  // Compromise: 4 quarters of px-values for ONE row = 64co*56px per block.
  // part2[((b*64+co)*56 + band)*4quarters... see below: we store the raw
  // per-px values summed over THIS block's 8 channels, indexed by px.
  {
    // write raw per-px partial (no BN/ReLU) for this row & quarter
    // layout: partpx[(((b*56 + band)*64 + co)*4 + ccq)*56 + px_global]
    // px_global = X0 + 0..13
  }
  const size_t base = ((((size_t)b*56 + band)*64 + co)*4 + ccq)*56 + X0;
#pragma unroll
  for (int px = 0; px < 14; ++px)
    part[base + px] = acc[px];
}

// ------- conv3 finish: sum 4 quarters, BN+ReLU, row-sum -> band partials ----
// grid (56 band, 16 b), 256 thr = 64 co x 4 x-slices of 14.
__global__ __launch_bounds__(256) void conv3_fin(
    const float* __restrict__ part, const float* __restrict__ su3,
    float* __restrict__ rowsum)
{
  const int band = blockIdx.x, b = blockIdx.y;
  const int tid = threadIdx.x;
  const int co = tid & 63, w = tid >> 6;
  __shared__ float red[4][64];
  const int X0 = w * 14;
  const size_t base = (((size_t)b*56 + band)*64 + co)*4*56;
  const float s = su3[co], u = su3[64+co];
  float sum = 0.f;
#pragma unroll
  for (int px = 0; px < 14; ++px) {
    const float v = part[base + X0 + px] + part[base + 56 + X0 + px]
                  + part[base + 112 + X0 + px] + part[base + 168 + X0 + px];
    sum += fmaxf(v*s + u, 0.f);
  }
  red[w][co] = sum;
  __syncthreads();
  if (tid < 64)
    rowsum[((size_t)b*64 + tid)*56 + band] =
        red[0][tid] + red[1][tid] + red[2][tid] + red[3][tid];
}

// ------------- global mean (56 partials) + FC + ReLU ------------------------
__global__ __launch_bounds__(128) void mean_fc(
    const float* __restrict__ rowsum, const float* __restrict__ fw,
    const float* __restrict__ fb, float* __restrict__ out)
{
  const int b = blockIdx.x;
  const int tid = threadIdx.x;
  __shared__ float h3s[64];
  if (tid < 64) {
    float s = 0.f;
    const float* pp = rowsum + ((size_t)b*64 + tid)*56;
#pragma unroll
    for (int i = 0; i < 56; ++i) s += pp[i];
    h3s[tid] = s * (1.0f / 3136.0f);
  }
  __syncthreads();
  float acc = fb[tid];
#pragma unroll
  for (int c = 0; c < 64; ++c)
    acc = fmaf(h3s[c], fw[tid*64 + c], acc);
  out[b*128 + tid] = fmaxf(acc, 0.f);
}

extern "C" void kernel_launch(void* const* d_in, const int* in_sizes, int n_in,
                              void* d_out, int out_size, void* d_ws, size_t ws_size,
                              hipStream_t stream) {
  const float* seq  = (const float*)d_in[0];
  const float* dcos = (const float*)d_in[1];
  const float* dsin = (const float*)d_in[2];
  const float* c1w  = (const float*)d_in[3];
  const float* c1b  = (const float*)d_in[4];
  const float* b1g  = (const float*)d_in[5];
  const float* b1b  = (const float*)d_in[6];
  const float* b1m  = (const float*)d_in[7];
  const float* b1v  = (const float*)d_in[8];
  const float* c2w  = (const float*)d_in[9];
  const float* c2b  = (const float*)d_in[10];
  const float* b2g  = (const float*)d_in[11];
  const float* b2b  = (const float*)d_in[12];
  const float* b2m  = (const float*)d_in[13];
  const float* b2v  = (const float*)d_in[14];
  const float* c3w  = (const float*)d_in[15];
  const float* c3b  = (const float*)d_in[16];
  const float* b3g  = (const float*)d_in[17];
  const float* b3b  = (const float*)d_in[18];
  const float* b3m  = (const float*)d_in[19];
  const float* b3v  = (const float*)d_in[20];
  const float* fw   = (const float*)d_in[21];
  const float* fb   = (const float*)d_in[22];
  float* out = (float*)d_out;

  float* ws   = (float*)d_ws;
  float* Cx   = ws;                   // 1,214,976 (113 rows x 224, 48 imgs)
  float* Sx   = ws + OFF_SX;          // 1,214,976
  float* spec = ws + OFF_SPEC;        // 2,408,448
  float* h1   = ws;                   // 3,211,264 (reuses dead Cx/Sx)
  float* h2   = ws + OFF_SPEC;        // 1,605,632 (reuses dead spec)
  float* wt3  = ws + OFF_WT;
  float* wt2  = ws + OFF_WT2;
  float* wt1  = ws + OFF_WT1;
  float* su3  = ws + OFF_SU3;
  float* su2  = ws + OFF_SU2;
  float* su1  = ws + OFF_SU1;
  float* part = ws + OFF_PART;        // 16*56*64*4*56 = 12.8M floats? NO —
  // part needs 16*56*64*4*56 = 12,845,056 floats = 51 MB. Place it in the
  // dead h1 region? h1 is DEAD after conv2. h1 region = ws+0 .. 3,211,264
  // (12.8 MB) — too small. Use ws + 7,225,344 onward (beyond spec+h2 live
  // region): h2 ends at OFF_SPEC+1,605,632 = 6,422,528. part at 6,422,528,
  // needs 12,845,056 -> ends 19,267,584 floats = 77 MB total ws. ws_size
  // is at least ~80MB in this harness (29MB used before; if insufficient
  // the bench errors visibly). Place conservatively at dead-h1 + beyond:
  part = ws;                           // reuse ws[0..] (h1 dead after conv2)
  // part spans 12,845,056 floats from ws[0] -> overlaps wt/su (at 3.2M)!
  // -> shift weights/su/rowsum to AFTER part instead:
  // (offsets recomputed below)
  float* partpx = ws + 6422528;        // after live h2; 12,845,056 floats
  float* rowsum = ws + OFF_PART;       // 57,344 floats (in old wt region gap)

  prep<<<24, 256, 0, stream>>>(c1w, c2w, c3w, c1b, c2b, c3b,
                               b1g, b1b, b1m, b1v, b2g, b2b, b2m, b2v,
                               b3g, b3b, b3m, b3v, wt3, wt2, wt1, su3, su2, su1);
  dft1<<<dim3(7, 4, 48), 256, 0, stream>>>(seq, dcos, dsin, Cx, Sx);
  dft2<<<dim3(4, 4, 48), 256, 0, stream>>>(Cx, Sx, dcos, dsin, spec);
  conv1<<<dim3(112, 16), 256, 0, stream>>>(spec, wt1, su1, h1);
  conv2<<<dim3(2, 56, 16), 256, 0, stream>>>(h1, wt2, su2, h2);
  conv3<<<dim3(4, 56, 16), 256, 0, stream>>>(h2, wt3, su3, partpx);
  conv3_fin<<<dim3(56, 16), 256, 0, stream>>>(partpx, su3, rowsum);
  mean_fc<<<16, 128, 0, stream>>>(rowsum, fw, fb, out);
}

// Round 14
// 176.003 us; speedup vs baseline: 1.0021x; 1.0021x over previous
//
#include <hip/hip_runtime.h>
#include <math.h>
#include <stddef.h>

#define N224 224
#define PIX 50176      // 224*224
#define ROWS113 25312  // 113*224, Cx/Sx rows per image

// ---- ws float offsets ----
#define OFF_SX    1214976
#define OFF_SPEC  4816896
#define OFF_WT    3211264              // right after h1 (16*16*112*112)
#define OFF_WT2   (OFF_WT + 24576)    // wt3v = 32*64*12
#define OFF_WT1   (OFF_WT + 30720)    // wt2v = 16*32*12
#define OFF_SU3   (OFF_WT + 31296)    // wt1v = 3*16*12
#define OFF_SU2   (OFF_WT + 31424)    // su3 = 128
#define OFF_SU1   (OFF_WT + 31488)    // su2 = 64
#define OFF_PART  (OFF_WT + 32768)    // 16*64*56 = 57344 floats

// ---------------- prep: weight transpose (vectorized layout) + BN fold ------
__global__ __launch_bounds__(256) void prep(
    const float* __restrict__ c1w, const float* __restrict__ c2w,
    const float* __restrict__ c3w, const float* __restrict__ c1b,
    const float* __restrict__ c2b, const float* __restrict__ c3b,
    const float* __restrict__ g1, const float* __restrict__ be1,
    const float* __restrict__ m1, const float* __restrict__ v1,
    const float* __restrict__ g2, const float* __restrict__ be2,
    const float* __restrict__ m2, const float* __restrict__ v2,
    const float* __restrict__ g3, const float* __restrict__ be3,
    const float* __restrict__ m3, const float* __restrict__ v3,
    float* __restrict__ wt3, float* __restrict__ wt2, float* __restrict__ wt1,
    float* __restrict__ su3, float* __restrict__ su2, float* __restrict__ su1)
{
  const int idx = blockIdx.x * 256 + threadIdx.x;
  const int stride = gridDim.x * 256;
  for (int i = idx; i < 32*64*12; i += stride) {       // wt3v[cc*768+co*12+k]
    const int cc = i / 768, r = i % 768, co = r / 12, k = r % 12;
    wt3[i] = (k < 9) ? c3w[co*288 + cc*9 + k] : 0.f;
  }
  for (int i = idx; i < 16*32*12; i += stride) {       // wt2v[cc*384+co*12+k]
    const int cc = i / 384, r = i % 384, co = r / 12, k = r % 12;
    wt2[i] = (k < 9) ? c2w[co*144 + cc*9 + k] : 0.f;
  }
  for (int i = idx; i < 3*16*12; i += stride) {        // wt1v[cc*192+co*12+k]
    const int cc = i / 192, r = i % 192, co = r / 12, k = r % 12;
    wt1[i] = (k < 9) ? c1w[co*27 + cc*9 + k] : 0.f;
  }
  if (idx < 64) {
    const float s = g3[idx] * rsqrtf(v3[idx] + 1e-5f);
    su3[idx] = s; su3[64+idx] = (c3b[idx] - m3[idx]) * s + be3[idx];
  } else if (idx < 96) {
    const int c = idx - 64;
    const float s = g2[c] * rsqrtf(v2[c] + 1e-5f);
    su2[c] = s; su2[32+c] = (c2b[c] - m2[c]) * s + be2[c];
  } else if (idx < 112) {
    const int c = idx - 96;
    const float s = g1[c] * rsqrtf(v1[c] + 1e-5f);
    su1[c] = s; su1[16+c] = (c1b[c] - m1[c]) * s + be1[c];
  }
}

// ---------------- DFT stage 1 (half rows): Cx = C @ x, Sx = S @ x -----------
__global__ __launch_bounds__(256) void dft1(
    const float* __restrict__ seq, const float* __restrict__ Cm,
    const float* __restrict__ Sm, float* __restrict__ Cx, float* __restrict__ Sx)
{
  const int p = blockIdx.z;
  const int b = p / 3, ch = p % 3;
  const float* __restrict__ x = seq + ((((size_t)b * 8 + 4) * 3 + ch) * PIX);
  const int i0 = blockIdx.y * 32;
  const int k0 = blockIdx.x * 32;
  const int tid = threadIdx.x;
  const int tx = tid & 15, ty = tid >> 4;
  __shared__ float Ctt[16][36], Stt[16][36], Xt[16][36];
  float aC[2][2] = {{0,0},{0,0}}, aS[2][2] = {{0,0},{0,0}};

  const int sidx = tid & 127;
  const int srow = sidx >> 2;
  const int skq  = (sidx & 3) * 4;
  const bool isC = tid < 128;
  const float* __restrict__ csb = (isC ? Cm : Sm) + (size_t)(i0 + srow) * N224 + skq;
  const int xjr = tid >> 4;
  const int xc  = (tid & 15) * 2;
  const float* __restrict__ xb = x + (size_t)xjr * N224 + k0 + xc;

  for (int jt = 0; jt < 14; ++jt) {
    const int j = jt * 16;
    __syncthreads();
    {
      const float4 v = *(const float4*)(csb + j);
      float (*dst)[36] = isC ? Ctt : Stt;
      dst[skq+0][srow] = v.x; dst[skq+1][srow] = v.y;
      dst[skq+2][srow] = v.z; dst[skq+3][srow] = v.w;
      *(float2*)&Xt[xjr][xc] = *(const float2*)(xb + (size_t)j * N224);
    }
    __syncthreads();
#pragma unroll
    for (int jj = 0; jj < 16; ++jj) {
      const float2 cv = *(const float2*)&Ctt[jj][2*ty];
      const float2 sv = *(const float2*)&Stt[jj][2*ty];
      const float2 xv = *(const float2*)&Xt[jj][2*tx];
      aC[0][0] = fmaf(cv.x, xv.x, aC[0][0]); aC[0][1] = fmaf(cv.x, xv.y, aC[0][1]);
      aC[1][0] = fmaf(cv.y, xv.x, aC[1][0]); aC[1][1] = fmaf(cv.y, xv.y, aC[1][1]);
      aS[0][0] = fmaf(sv.x, xv.x, aS[0][0]); aS[0][1] = fmaf(sv.x, xv.y, aS[0][1]);
      aS[1][0] = fmaf(sv.y, xv.x, aS[1][0]); aS[1][1] = fmaf(sv.y, xv.y, aS[1][1]);
    }
  }
  const size_t b113 = (size_t)p * ROWS113;
#pragma unroll
  for (int a = 0; a < 2; ++a) {
    const int i = i0 + 2*ty + a;
    if (i <= 112) {
      const size_t off = b113 + (size_t)i * N224 + k0 + 2*tx;
      *(float2*)&Cx[off] = make_float2(aC[a][0], aC[a][1]);
      *(float2*)&Sx[off] = make_float2(aS[a][0], aS[a][1]);
    }
  }
}

// --------- DFT stage 2 (QUARTER grid): log|X| + fftshift, 4-way mirror ------
__global__ __launch_bounds__(256) void dft2(
    const float* __restrict__ Cx, const float* __restrict__ Sx,
    const float* __restrict__ Cm, const float* __restrict__ Sm,
    float* __restrict__ spec)
{
  const int p = blockIdx.z;
  const int i0 = blockIdx.y * 32;
  const int k0 = blockIdx.x * 32;
  const int tid = threadIdx.x;
  const int tx = tid & 15, ty = tid >> 4;
  const size_t b113 = (size_t)p * ROWS113;
  __shared__ float CxT[16][36], SxT[16][36], Ct[16][36], St[16][36];
  float p1[2][2] = {{0,0},{0,0}}, p2[2][2] = {{0,0},{0,0}};
  float p3[2][2] = {{0,0},{0,0}}, p4[2][2] = {{0,0},{0,0}};

  const int sidx = tid & 127;
  const int srow = sidx >> 2;
  const int skq  = (sidx & 3) * 4;
  const bool isCx = tid < 128;
  const int ri = (i0 + srow > 112) ? 112 : i0 + srow;
  const float* __restrict__ ab = (isCx ? Cx : Sx) + b113 + (size_t)ri * N224 + skq;
  const int jr = tid >> 4;
  const int cc2 = (tid & 15) * 2;
  const float* __restrict__ cb = Cm + (size_t)jr * N224 + k0 + cc2;
  const float* __restrict__ sb2 = Sm + (size_t)jr * N224 + k0 + cc2;

  for (int jt = 0; jt < 14; ++jt) {
    const int j = jt * 16;
    __syncthreads();
    {
      const float4 v = *(const float4*)(ab + j);
      float (*dst)[36] = isCx ? CxT : SxT;
      dst[skq+0][srow] = v.x; dst[skq+1][srow] = v.y;
      dst[skq+2][srow] = v.z; dst[skq+3][srow] = v.w;
      *(float2*)&Ct[jr][cc2] = *(const float2*)(cb + (size_t)j * N224);
      *(float2*)&St[jr][cc2] = *(const float2*)(sb2 + (size_t)j * N224);
    }
    __syncthreads();
#pragma unroll
    for (int jj = 0; jj < 16; ++jj) {
      const float2 cxv = *(const float2*)&CxT[jj][2*ty];
      const float2 sxv = *(const float2*)&SxT[jj][2*ty];
      const float2 ccv = *(const float2*)&Ct[jj][2*tx];
      const float2 ssv = *(const float2*)&St[jj][2*tx];
      const float cxa[2] = {cxv.x, cxv.y};
      const float sxa[2] = {sxv.x, sxv.y};
      const float cca[2] = {ccv.x, ccv.y};
      const float ssa[2] = {ssv.x, ssv.y};
#pragma unroll
      for (int a = 0; a < 2; ++a)
#pragma unroll
        for (int d = 0; d < 2; ++d) {
          p1[a][d] = fmaf(cxa[a], cca[d], p1[a][d]);
          p2[a][d] = fmaf(sxa[a], ssa[d], p2[a][d]);
          p3[a][d] = fmaf(cxa[a], ssa[d], p3[a][d]);
          p4[a][d] = fmaf(sxa[a], cca[d], p4[a][d]);
        }
    }
  }
  const size_t sb = (size_t)p * PIX;
#pragma unroll
  for (int a = 0; a < 2; ++a) {
    const int i = i0 + 2*ty + a;
    if (i > 112) continue;
    const int shi  = (i < 112) ? i + 112 : i - 112;
    const int shmi = 112 - i;
    const bool irm = (i >= 1) && (i <= 111);
#pragma unroll
    for (int d = 0; d < 2; ++d) {
      const int k = k0 + 2*tx + d;
      if (k > 112) continue;
      const float r1 = p1[a][d] - p2[a][d];
      const float i1 = p3[a][d] + p4[a][d];
      const float sp1v = logf(sqrtf(fmaf(r1, r1, fmaf(i1, i1, 1e-8f))) + 1e-8f);
      const float r2v = p1[a][d] + p2[a][d];
      const float i2v = p3[a][d] - p4[a][d];
      const float sp2v = logf(sqrtf(fmaf(r2v, r2v, fmaf(i2v, i2v, 1e-8f))) + 1e-8f);
      const int shk  = (k < 112) ? k + 112 : k - 112;
      const int shmk = 112 - k;
      const bool krm = (k >= 1) && (k <= 111);
      spec[sb + (size_t)shi*N224 + shk] = sp1v;
      if (irm)        spec[sb + (size_t)shmi*N224 + shk ] = sp2v;
      if (krm)        spec[sb + (size_t)shi *N224 + shmk] = sp2v;
      if (irm && krm) spec[sb + (size_t)shmi*N224 + shmk] = sp1v;
    }
  }
}

// -------- conv1 (3->16)+BN+ReLU+pool: lane-cr split, shfl pool --------------
__global__ __launch_bounds__(256) void conv1(
    const float* __restrict__ spec, const float* __restrict__ wt1,
    const float* __restrict__ su1, float* __restrict__ out)
{
  const int band = blockIdx.x, b = blockIdx.y;
  const int tid = threadIdx.x;
  const int lane = tid & 63, w = tid >> 6;
  const int co = lane & 15, cr = (lane >> 4) & 1, xs = lane >> 5;
  const int xh = w >> 1, xq = w & 1;
  __shared__ float in_t[3][4][232];
  for (int i = tid; i < 3*4*232; i += 256) {
    const int c = i % 232, r = (i / 232) % 4, cc = i / 928;
    const int y = band*2 - 1 + r, gx = c - 1;
    float v = 0.f;
    if (c < 226 && y >= 0 && y < 224 && gx >= 0 && gx < 224)
      v = spec[((size_t)b*3 + cc) * PIX + (size_t)y * N224 + gx];
    in_t[cc][r][c] = v;
  }
  __syncthreads();
  const int X0 = xh*112 + xq*56 + xs*28;
  float acc[28];
#pragma unroll
  for (int px = 0; px < 28; ++px) acc[px] = 0.f;
#pragma unroll
  for (int cc = 0; cc < 3; ++cc) {
    const float4 w0 = *(const float4*)&wt1[cc*192 + co*12];
    const float4 w1 = *(const float4*)&wt1[cc*192 + co*12 + 4];
    const float  w8 = wt1[cc*192 + co*12 + 8];
    const float wr[9] = {w0.x, w0.y, w0.z, w0.w, w1.x, w1.y, w1.z, w1.w, w8};
#pragma unroll
    for (int ky = 0; ky < 3; ++ky) {
      float xr[32];
      const float4* rp = (const float4*)&in_t[cc][cr + ky][X0];
#pragma unroll
      for (int t = 0; t < 8; ++t) {
        const float4 v = rp[t];
        xr[4*t]=v.x; xr[4*t+1]=v.y; xr[4*t+2]=v.z; xr[4*t+3]=v.w;
      }
#pragma unroll
      for (int px = 0; px < 28; ++px) {
        acc[px] = fmaf(xr[px  ], wr[ky*3  ], acc[px]);
        acc[px] = fmaf(xr[px+1], wr[ky*3+1], acc[px]);
        acc[px] = fmaf(xr[px+2], wr[ky*3+2], acc[px]);
      }
    }
  }
  const float s = su1[co], u = su1[16+co];
  float m[14];
#pragma unroll
  for (int p = 0; p < 14; ++p)
    m[p] = fmaxf(acc[2*p]*s + u, acc[2*p+1]*s + u);
#pragma unroll
  for (int p = 0; p < 14; ++p) {
    const float pm = __shfl_xor(m[p], 16);
    m[p] = fmaxf(fmaxf(m[p], pm), 0.f);
  }
  if (cr == 0) {
    const int pxb = X0 >> 1;
    float* op = &out[(((size_t)b*16 + co)*112 + band)*112 + pxb];
#pragma unroll
    for (int p = 0; p < 14; ++p) op[p] = m[p];
  }
}

// -------- conv2 (16->32)+BN+ReLU+pool: cr-split -----------------------------
__global__ __launch_bounds__(256) void conv2(
    const float* __restrict__ h1, const float* __restrict__ wt2,
    const float* __restrict__ su2, float* __restrict__ out)
{
  const int xh = blockIdx.x, band = blockIdx.y, b = blockIdx.z;
  const int tid = threadIdx.x;
  const int lane = tid & 63, w = tid >> 6;
  const int co = lane & 31, cr = lane >> 5;
  __shared__ float in_t[16][4][64];
  for (int i = tid; i < 16*4*58; i += 256) {
    const int c = i % 58, r = (i / 58) % 4, cc = i / 232;
    const int y = band*2 - 1 + r, gx = xh*56 - 1 + c;
    float v = 0.f;
    if (y >= 0 && y < 112 && gx >= 0 && gx < 112)
      v = h1[(((size_t)b*16 + cc)*112 + y)*112 + gx];
    in_t[cc][r][c] = v;
  }
  __syncthreads();
  const int X0 = w * 14;                   // 0,14,28,42 — 8B-aligned
  float acc[14];
#pragma unroll
  for (int px = 0; px < 14; ++px) acc[px] = 0.f;
  const float* __restrict__ wp = wt2 + co*12;
  float4 nw0 = *(const float4*)(wp);
  float4 nw1 = *(const float4*)(wp + 4);
  float  nw8 = wp[8];
  for (int cc = 0; cc < 16; ++cc) {
    const float4 w0 = nw0, w1 = nw1; const float w8 = nw8;
    if (cc < 15) {
      const float* np = wp + (cc + 1) * 384;
      nw0 = *(const float4*)(np);
      nw1 = *(const float4*)(np + 4);
      nw8 = np[8];
    }
    const float wr[9] = {w0.x, w0.y, w0.z, w0.w, w1.x, w1.y, w1.z, w1.w, w8};
    float xr[3][16];
#pragma unroll
    for (int ky = 0; ky < 3; ++ky) {
      const float2* rp = (const float2*)&in_t[cc][cr + ky][X0];
#pragma unroll
      for (int t = 0; t < 8; ++t) {
        const float2 v = rp[t];
        xr[ky][2*t] = v.x; xr[ky][2*t+1] = v.y;
      }
    }
#pragma unroll
    for (int ky = 0; ky < 3; ++ky)
#pragma unroll
      for (int px = 0; px < 14; ++px) {
        acc[px] = fmaf(xr[ky][px  ], wr[ky*3  ], acc[px]);
        acc[px] = fmaf(xr[ky][px+1], wr[ky*3+1], acc[px]);
        acc[px] = fmaf(xr[ky][px+2], wr[ky*3+2], acc[px]);
      }
  }
  const float s = su2[co], u = su2[32+co];
  float m[7];
#pragma unroll
  for (int p = 0; p < 7; ++p)
    m[p] = fmaxf(acc[2*p]*s + u, acc[2*p+1]*s + u);
#pragma unroll
  for (int p = 0; p < 7; ++p) {
    const float pm = __shfl_xor(m[p], 32);
    m[p] = fmaxf(fmaxf(m[p], pm), 0.f);
  }
  if (cr == 0) {
    float* op = &out[(((size_t)b*32 + co)*56 + band)*56 + xh*28 + w*7];
#pragma unroll
    for (int p = 0; p < 7; ++p) op[p] = m[p];
  }
}

// -------- conv3 (32->64)+BN+ReLU+partial mean: NO LDS, scalar-broadcast -----
// grid (56 row, 16 b), 256 thr = 64 co x 4 x-slices of 14.
// Within a wave all 64 lanes share the x-slice -> input rows are WAVE-UNIFORM.
// Load them via a readfirstlane-uniformed pointer (scalar / broadcast path);
// no __shared__ staging, no barrier, no ds_read stream.
__global__ __launch_bounds__(256) void conv3(
    const float* __restrict__ h2, const float* __restrict__ wt3,
    const float* __restrict__ su3, float* __restrict__ part)
{
  const int band = blockIdx.x, b = blockIdx.y;
  const int tid = threadIdx.x;
  const int co = tid & 63, w = tid >> 6;
  const int wu = __builtin_amdgcn_readfirstlane(w);   // wave-uniform 0..3
  __shared__ float red[4][64];
  const int X0 = wu * 14;
  const int g0 = (wu == 0) ? 0 : X0 - 1;              // 0,13,27,41
  float acc[14];
#pragma unroll
  for (int px = 0; px < 14; ++px) acc[px] = 0.f;
  const float* __restrict__ wp = wt3 + co*12;
  float4 nw0 = *(const float4*)(wp);
  float4 nw1 = *(const float4*)(wp + 4);
  float  nw8 = wp[8];
  const float* __restrict__ hb = h2 + ((size_t)b*32*56 + (size_t)(band-1)*56) * 1 + g0;
  for (int cc = 0; cc < 32; ++cc) {
    const float4 w0 = nw0, w1 = nw1; const float w8 = nw8;
    if (cc < 31) {
      const float* np = wp + (cc + 1) * 768;
      nw0 = *(const float4*)(np);
      nw1 = *(const float4*)(np + 4);
      nw8 = np[8];
    }
    const float wr[9] = {w0.x, w0.y, w0.z, w0.w, w1.x, w1.y, w1.z, w1.w, w8};
    float xv[3][16];
#pragma unroll
    for (int rr = 0; rr < 3; ++rr) {
      const int y = band - 1 + rr;
      if (y >= 0 && y < 56) {
        const float* __restrict__ rp =
            h2 + (((size_t)b*32 + cc)*56 + y)*56 + g0;
#pragma unroll
        for (int j = 0; j < 16; ++j) xv[rr][j] = rp[j];
      } else {
#pragma unroll
        for (int j = 0; j < 16; ++j) xv[rr][j] = 0.f;
      }
    }
    if (wu == 0) {          // shift right: col -1 is zero pad
#pragma unroll
      for (int rr = 0; rr < 3; ++rr) {
#pragma unroll
        for (int t = 15; t >= 1; --t) xv[rr][t] = xv[rr][t-1];
        xv[rr][0] = 0.f;
      }
    } else if (wu == 3) {   // col 56 is zero pad
#pragma unroll
      for (int rr = 0; rr < 3; ++rr) xv[rr][15] = 0.f;
    }
#pragma unroll
    for (int rr = 0; rr < 3; ++rr)
#pragma unroll
      for (int px = 0; px < 14; ++px) {
        acc[px] = fmaf(xv[rr][px  ], wr[rr*3  ], acc[px]);
        acc[px] = fmaf(xv[rr][px+1], wr[rr*3+1], acc[px]);
        acc[px] = fmaf(xv[rr][px+2], wr[rr*3+2], acc[px]);
      }
  }
  (void)hb;
  const float s = su3[co], u = su3[64+co];
  float sum = 0.f;
#pragma unroll
  for (int px = 0; px < 14; ++px)
    sum += fmaxf(acc[px]*s + u, 0.f);
  red[w][co] = sum;
  __syncthreads();
  if (tid < 64)
    part[((size_t)b*64 + co)*56 + band] =
        red[0][co] + red[1][co] + red[2][co] + red[3][co];
}

// ------------- global mean (56 partials) + FC + ReLU ------------------------
__global__ __launch_bounds__(128) void mean_fc(
    const float* __restrict__ part, const float* __restrict__ fw,
    const float* __restrict__ fb, float* __restrict__ out)
{
  const int b = blockIdx.x;
  const int tid = threadIdx.x;
  __shared__ float h3s[64];
  if (tid < 64) {
    float s = 0.f;
    const float* pp = part + ((size_t)b*64 + tid)*56;
#pragma unroll
    for (int i = 0; i < 56; ++i) s += pp[i];
    h3s[tid] = s * (1.0f / 3136.0f);
  }
  __syncthreads();
  float acc = fb[tid];
#pragma unroll
  for (int c = 0; c < 64; ++c)
    acc = fmaf(h3s[c], fw[tid*64 + c], acc);
  out[b*128 + tid] = fmaxf(acc, 0.f);
}

extern "C" void kernel_launch(void* const* d_in, const int* in_sizes, int n_in,
                              void* d_out, int out_size, void* d_ws, size_t ws_size,
                              hipStream_t stream) {
  const float* seq  = (const float*)d_in[0];
  const float* dcos = (const float*)d_in[1];
  const float* dsin = (const float*)d_in[2];
  const float* c1w  = (const float*)d_in[3];
  const float* c1b  = (const float*)d_in[4];
  const float* b1g  = (const float*)d_in[5];
  const float* b1b  = (const float*)d_in[6];
  const float* b1m  = (const float*)d_in[7];
  const float* b1v  = (const float*)d_in[8];
  const float* c2w  = (const float*)d_in[9];
  const float* c2b  = (const float*)d_in[10];
  const float* b2g  = (const float*)d_in[11];
  const float* b2b  = (const float*)d_in[12];
  const float* b2m  = (const float*)d_in[13];
  const float* b2v  = (const float*)d_in[14];
  const float* c3w  = (const float*)d_in[15];
  const float* c3b  = (const float*)d_in[16];
  const float* b3g  = (const float*)d_in[17];
  const float* b3b  = (const float*)d_in[18];
  const float* b3m  = (const float*)d_in[19];
  const float* b3v  = (const float*)d_in[20];
  const float* fw   = (const float*)d_in[21];
  const float* fb   = (const float*)d_in[22];
  float* out = (float*)d_out;

  float* ws   = (float*)d_ws;
  float* Cx   = ws;                   // 1,214,976 (113 rows x 224, 48 imgs)
  float* Sx   = ws + OFF_SX;          // 1,214,976
  float* spec = ws + OFF_SPEC;        // 2,408,448
  float* h1   = ws;                   // 3,211,264 (reuses dead Cx/Sx)
  float* h2   = ws + OFF_SPEC;        // 1,605,632 (reuses dead spec)
  float* wt3  = ws + OFF_WT;
  float* wt2  = ws + OFF_WT2;
  float* wt1  = ws + OFF_WT1;
  float* su3  = ws + OFF_SU3;
  float* su2  = ws + OFF_SU2;
  float* su1  = ws + OFF_SU1;
  float* part = ws + OFF_PART;        // 57,344

  prep<<<24, 256, 0, stream>>>(c1w, c2w, c3w, c1b, c2b, c3b,
                               b1g, b1b, b1m, b1v, b2g, b2b, b2m, b2v,
                               b3g, b3b, b3m, b3v, wt3, wt2, wt1, su3, su2, su1);
  dft1<<<dim3(7, 4, 48), 256, 0, stream>>>(seq, dcos, dsin, Cx, Sx);
  dft2<<<dim3(4, 4, 48), 256, 0, stream>>>(Cx, Sx, dcos, dsin, spec);
  conv1<<<dim3(112, 16), 256, 0, stream>>>(spec, wt1, su1, h1);
  conv2<<<dim3(2, 56, 16), 256, 0, stream>>>(h1, wt2, su2, h2);
  conv3<<<dim3(56, 16), 256, 0, stream>>>(h2, wt3, su3, part);
  mean_fc<<<16, 128, 0, stream>>>(part, fw, fb, out);
}

// Round 16
// 163.689 us; speedup vs baseline: 1.0775x; 1.0752x over previous
//
#include <hip/hip_runtime.h>
#include <math.h>
#include <stddef.h>

#define N224 224
#define PIX 50176      // 224*224
#define ROWS113 25312  // 113*224, Cx/Sx rows per image

// ---- ws float offsets ----
#define OFF_SX    1214976
#define OFF_SPEC  4816896
#define OFF_WT    3211264              // right after h1 (16*16*112*112)
#define OFF_WT2   (OFF_WT + 24576)    // wt3v = 32*64*12
#define OFF_WT1   (OFF_WT + 30720)    // wt2v = 16*32*12
#define OFF_SU3   (OFF_WT + 31296)    // wt1v = 3*16*12
#define OFF_SU2   (OFF_WT + 31424)    // su3 = 128
#define OFF_SU1   (OFF_WT + 31488)    // su2 = 64
#define OFF_PART  (OFF_WT + 32768)    // 16*64*56 = 57344 floats

// ---------------- prep: weight transpose (vectorized layout) + BN fold ------
__global__ __launch_bounds__(256) void prep(
    const float* __restrict__ c1w, const float* __restrict__ c2w,
    const float* __restrict__ c3w, const float* __restrict__ c1b,
    const float* __restrict__ c2b, const float* __restrict__ c3b,
    const float* __restrict__ g1, const float* __restrict__ be1,
    const float* __restrict__ m1, const float* __restrict__ v1,
    const float* __restrict__ g2, const float* __restrict__ be2,
    const float* __restrict__ m2, const float* __restrict__ v2,
    const float* __restrict__ g3, const float* __restrict__ be3,
    const float* __restrict__ m3, const float* __restrict__ v3,
    float* __restrict__ wt3, float* __restrict__ wt2, float* __restrict__ wt1,
    float* __restrict__ su3, float* __restrict__ su2, float* __restrict__ su1)
{
  const int idx = blockIdx.x * 256 + threadIdx.x;
  const int stride = gridDim.x * 256;
  for (int i = idx; i < 32*64*12; i += stride) {       // wt3v[cc*768+co*12+k]
    const int cc = i / 768, r = i % 768, co = r / 12, k = r % 12;
    wt3[i] = (k < 9) ? c3w[co*288 + cc*9 + k] : 0.f;
  }
  for (int i = idx; i < 16*32*12; i += stride) {       // wt2v[cc*384+co*12+k]
    const int cc = i / 384, r = i % 384, co = r / 12, k = r % 12;
    wt2[i] = (k < 9) ? c2w[co*144 + cc*9 + k] : 0.f;
  }
  for (int i = idx; i < 3*16*12; i += stride) {        // wt1v[cc*192+co*12+k]
    const int cc = i / 192, r = i % 192, co = r / 12, k = r % 12;
    wt1[i] = (k < 9) ? c1w[co*27 + cc*9 + k] : 0.f;
  }
  if (idx < 64) {
    const float s = g3[idx] * rsqrtf(v3[idx] + 1e-5f);
    su3[idx] = s; su3[64+idx] = (c3b[idx] - m3[idx]) * s + be3[idx];
  } else if (idx < 96) {
    const int c = idx - 64;
    const float s = g2[c] * rsqrtf(v2[c] + 1e-5f);
    su2[c] = s; su2[32+c] = (c2b[c] - m2[c]) * s + be2[c];
  } else if (idx < 112) {
    const int c = idx - 96;
    const float s = g1[c] * rsqrtf(v1[c] + 1e-5f);
    su1[c] = s; su1[16+c] = (c1b[c] - m1[c]) * s + be1[c];
  }
}

// ---------------- DFT stage 1 (half rows): Cx = C @ x, Sx = S @ x -----------
__global__ __launch_bounds__(256) void dft1(
    const float* __restrict__ seq, const float* __restrict__ Cm,
    const float* __restrict__ Sm, float* __restrict__ Cx, float* __restrict__ Sx)
{
  const int p = blockIdx.z;
  const int b = p / 3, ch = p % 3;
  const float* __restrict__ x = seq + ((((size_t)b * 8 + 4) * 3 + ch) * PIX);
  const int i0 = blockIdx.y * 32;
  const int k0 = blockIdx.x * 32;
  const int tid = threadIdx.x;
  const int tx = tid & 15, ty = tid >> 4;
  __shared__ float Ctt[16][36], Stt[16][36], Xt[16][36];
  float aC[2][2] = {{0,0},{0,0}}, aS[2][2] = {{0,0},{0,0}};

  const int sidx = tid & 127;
  const int srow = sidx >> 2;
  const int skq  = (sidx & 3) * 4;
  const bool isC = tid < 128;
  const float* __restrict__ csb = (isC ? Cm : Sm) + (size_t)(i0 + srow) * N224 + skq;
  const int xjr = tid >> 4;
  const int xc  = (tid & 15) * 2;
  const float* __restrict__ xb = x + (size_t)xjr * N224 + k0 + xc;

  for (int jt = 0; jt < 14; ++jt) {
    const int j = jt * 16;
    __syncthreads();
    {
      const float4 v = *(const float4*)(csb + j);
      float (*dst)[36] = isC ? Ctt : Stt;
      dst[skq+0][srow] = v.x; dst[skq+1][srow] = v.y;
      dst[skq+2][srow] = v.z; dst[skq+3][srow] = v.w;
      *(float2*)&Xt[xjr][xc] = *(const float2*)(xb + (size_t)j * N224);
    }
    __syncthreads();
#pragma unroll
    for (int jj = 0; jj < 16; ++jj) {
      const float2 cv = *(const float2*)&Ctt[jj][2*ty];
      const float2 sv = *(const float2*)&Stt[jj][2*ty];
      const float2 xv = *(const float2*)&Xt[jj][2*tx];
      aC[0][0] = fmaf(cv.x, xv.x, aC[0][0]); aC[0][1] = fmaf(cv.x, xv.y, aC[0][1]);
      aC[1][0] = fmaf(cv.y, xv.x, aC[1][0]); aC[1][1] = fmaf(cv.y, xv.y, aC[1][1]);
      aS[0][0] = fmaf(sv.x, xv.x, aS[0][0]); aS[0][1] = fmaf(sv.x, xv.y, aS[0][1]);
      aS[1][0] = fmaf(sv.y, xv.x, aS[1][0]); aS[1][1] = fmaf(sv.y, xv.y, aS[1][1]);
    }
  }
  const size_t b113 = (size_t)p * ROWS113;
#pragma unroll
  for (int a = 0; a < 2; ++a) {
    const int i = i0 + 2*ty + a;
    if (i <= 112) {
      const size_t off = b113 + (size_t)i * N224 + k0 + 2*tx;
      *(float2*)&Cx[off] = make_float2(aC[a][0], aC[a][1]);
      *(float2*)&Sx[off] = make_float2(aS[a][0], aS[a][1]);
    }
  }
}

// --------- DFT stage 2 (QUARTER grid): log|X| + fftshift, 4-way mirror ------
__global__ __launch_bounds__(256) void dft2(
    const float* __restrict__ Cx, const float* __restrict__ Sx,
    const float* __restrict__ Cm, const float* __restrict__ Sm,
    float* __restrict__ spec)
{
  const int p = blockIdx.z;
  const int i0 = blockIdx.y * 32;
  const int k0 = blockIdx.x * 32;
  const int tid = threadIdx.x;
  const int tx = tid & 15, ty = tid >> 4;
  const size_t b113 = (size_t)p * ROWS113;
  __shared__ float CxT[16][36], SxT[16][36], Ct[16][36], St[16][36];
  float p1[2][2] = {{0,0},{0,0}}, p2[2][2] = {{0,0},{0,0}};
  float p3[2][2] = {{0,0},{0,0}}, p4[2][2] = {{0,0},{0,0}};

  const int sidx = tid & 127;
  const int srow = sidx >> 2;
  const int skq  = (sidx & 3) * 4;
  const bool isCx = tid < 128;
  const int ri = (i0 + srow > 112) ? 112 : i0 + srow;
  const float* __restrict__ ab = (isCx ? Cx : Sx) + b113 + (size_t)ri * N224 + skq;
  const int jr = tid >> 4;
  const int cc2 = (tid & 15) * 2;
  const float* __restrict__ cb = Cm + (size_t)jr * N224 + k0 + cc2;
  const float* __restrict__ sb2 = Sm + (size_t)jr * N224 + k0 + cc2;

  for (int jt = 0; jt < 14; ++jt) {
    const int j = jt * 16;
    __syncthreads();
    {
      const float4 v = *(const float4*)(ab + j);
      float (*dst)[36] = isCx ? CxT : SxT;
      dst[skq+0][srow] = v.x; dst[skq+1][srow] = v.y;
      dst[skq+2][srow] = v.z; dst[skq+3][srow] = v.w;
      *(float2*)&Ct[jr][cc2] = *(const float2*)(cb + (size_t)j * N224);
      *(float2*)&St[jr][cc2] = *(const float2*)(sb2 + (size_t)j * N224);
    }
    __syncthreads();
#pragma unroll
    for (int jj = 0; jj < 16; ++jj) {
      const float2 cxv = *(const float2*)&CxT[jj][2*ty];
      const float2 sxv = *(const float2*)&SxT[jj][2*ty];
      const float2 ccv = *(const float2*)&Ct[jj][2*tx];
      const float2 ssv = *(const float2*)&St[jj][2*tx];
      const float cxa[2] = {cxv.x, cxv.y};
      const float sxa[2] = {sxv.x, sxv.y};
      const float cca[2] = {ccv.x, ccv.y};
      const float ssa[2] = {ssv.x, ssv.y};
#pragma unroll
      for (int a = 0; a < 2; ++a)
#pragma unroll
        for (int d = 0; d < 2; ++d) {
          p1[a][d] = fmaf(cxa[a], cca[d], p1[a][d]);
          p2[a][d] = fmaf(sxa[a], ssa[d], p2[a][d]);
          p3[a][d] = fmaf(cxa[a], ssa[d], p3[a][d]);
          p4[a][d] = fmaf(sxa[a], cca[d], p4[a][d]);
        }
    }
  }
  const size_t sb = (size_t)p * PIX;
#pragma unroll
  for (int a = 0; a < 2; ++a) {
    const int i = i0 + 2*ty + a;
    if (i > 112) continue;
    const int shi  = (i < 112) ? i + 112 : i - 112;
    const int shmi = 112 - i;
    const bool irm = (i >= 1) && (i <= 111);
#pragma unroll
    for (int d = 0; d < 2; ++d) {
      const int k = k0 + 2*tx + d;
      if (k > 112) continue;
      const float r1 = p1[a][d] - p2[a][d];
      const float i1 = p3[a][d] + p4[a][d];
      const float sp1v = logf(sqrtf(fmaf(r1, r1, fmaf(i1, i1, 1e-8f))) + 1e-8f);
      const float r2v = p1[a][d] + p2[a][d];
      const float i2v = p3[a][d] - p4[a][d];
      const float sp2v = logf(sqrtf(fmaf(r2v, r2v, fmaf(i2v, i2v, 1e-8f))) + 1e-8f);
      const int shk  = (k < 112) ? k + 112 : k - 112;
      const int shmk = 112 - k;
      const bool krm = (k >= 1) && (k <= 111);
      spec[sb + (size_t)shi*N224 + shk] = sp1v;
      if (irm)        spec[sb + (size_t)shmi*N224 + shk ] = sp2v;
      if (krm)        spec[sb + (size_t)shi *N224 + shmk] = sp2v;
      if (irm && krm) spec[sb + (size_t)shmi*N224 + shmk] = sp1v;
    }
  }
}

// -------- conv1 (3->16)+BN+ReLU+pool: lane-cr split, shfl pool --------------
__global__ __launch_bounds__(256) void conv1(
    const float* __restrict__ spec, const float* __restrict__ wt1,
    const float* __restrict__ su1, float* __restrict__ out)
{
  const int band = blockIdx.x, b = blockIdx.y;
  const int tid = threadIdx.x;
  const int lane = tid & 63, w = tid >> 6;
  const int co = lane & 15, cr = (lane >> 4) & 1, xs = lane >> 5;
  const int xh = w >> 1, xq = w & 1;
  __shared__ float in_t[3][4][232];
  for (int i = tid; i < 3*4*232; i += 256) {
    const int c = i % 232, r = (i / 232) % 4, cc = i / 928;
    const int y = band*2 - 1 + r, gx = c - 1;
    float v = 0.f;
    if (c < 226 && y >= 0 && y < 224 && gx >= 0 && gx < 224)
      v = spec[((size_t)b*3 + cc) * PIX + (size_t)y * N224 + gx];
    in_t[cc][r][c] = v;
  }
  __syncthreads();
  const int X0 = xh*112 + xq*56 + xs*28;
  float acc[28];
#pragma unroll
  for (int px = 0; px < 28; ++px) acc[px] = 0.f;
#pragma unroll
  for (int cc = 0; cc < 3; ++cc) {
    const float4 w0 = *(const float4*)&wt1[cc*192 + co*12];
    const float4 w1 = *(const float4*)&wt1[cc*192 + co*12 + 4];
    const float  w8 = wt1[cc*192 + co*12 + 8];
    const float wr[9] = {w0.x, w0.y, w0.z, w0.w, w1.x, w1.y, w1.z, w1.w, w8};
#pragma unroll
    for (int ky = 0; ky < 3; ++ky) {
      float xr[32];
      const float4* rp = (const float4*)&in_t[cc][cr + ky][X0];
#pragma unroll
      for (int t = 0; t < 8; ++t) {
        const float4 v = rp[t];
        xr[4*t]=v.x; xr[4*t+1]=v.y; xr[4*t+2]=v.z; xr[4*t+3]=v.w;
      }
#pragma unroll
      for (int px = 0; px < 28; ++px) {
        acc[px] = fmaf(xr[px  ], wr[ky*3  ], acc[px]);
        acc[px] = fmaf(xr[px+1], wr[ky*3+1], acc[px]);
        acc[px] = fmaf(xr[px+2], wr[ky*3+2], acc[px]);
      }
    }
  }
  const float s = su1[co], u = su1[16+co];
  float m[14];
#pragma unroll
  for (int p = 0; p < 14; ++p)
    m[p] = fmaxf(acc[2*p]*s + u, acc[2*p+1]*s + u);
#pragma unroll
  for (int p = 0; p < 14; ++p) {
    const float pm = __shfl_xor(m[p], 16);
    m[p] = fmaxf(fmaxf(m[p], pm), 0.f);
  }
  if (cr == 0) {
    const int pxb = X0 >> 1;
    float* op = &out[(((size_t)b*16 + co)*112 + band)*112 + pxb];
#pragma unroll
    for (int p = 0; p < 14; ++p) op[p] = m[p];
  }
}

// -------- conv2 (16->32)+BN+ReLU+pool: weight prefetch double-buffer --------
__global__ __launch_bounds__(256) void conv2(
    const float* __restrict__ h1, const float* __restrict__ wt2,
    const float* __restrict__ su2, float* __restrict__ out)
{
  const int xh = blockIdx.x, band = blockIdx.y, b = blockIdx.z;
  const int tid = threadIdx.x;
  const int lane = tid & 63, w = tid >> 6;
  const int co = lane & 31, cr = lane >> 5;
  __shared__ float in_t[16][4][64];
  for (int i = tid; i < 16*4*58; i += 256) {
    const int c = i % 58, r = (i / 58) % 4, cc = i / 232;
    const int y = band*2 - 1 + r, gx = xh*56 - 1 + c;
    float v = 0.f;
    if (y >= 0 && y < 112 && gx >= 0 && gx < 112)
      v = h1[(((size_t)b*16 + cc)*112 + y)*112 + gx];
    in_t[cc][r][c] = v;
  }
  __syncthreads();
  const int X0 = w * 14;                   // 0,14,28,42 — 8B-aligned
  float acc[14];
#pragma unroll
  for (int px = 0; px < 14; ++px) acc[px] = 0.f;
  const float* __restrict__ wp = wt2 + co*12;
  float4 nw0 = *(const float4*)(wp);
  float4 nw1 = *(const float4*)(wp + 4);
  float  nw8 = wp[8];
  for (int cc = 0; cc < 16; ++cc) {
    const float4 w0 = nw0, w1 = nw1; const float w8 = nw8;
    if (cc < 15) {
      const float* np = wp + (cc + 1) * 384;
      nw0 = *(const float4*)(np);
      nw1 = *(const float4*)(np + 4);
      nw8 = np[8];
    }
    const float wr[9] = {w0.x, w0.y, w0.z, w0.w, w1.x, w1.y, w1.z, w1.w, w8};
#pragma unroll
    for (int ky = 0; ky < 3; ++ky) {
      float xr[16];
      const float2* rp = (const float2*)&in_t[cc][cr + ky][X0];
#pragma unroll
      for (int t = 0; t < 8; ++t) {
        const float2 v = rp[t];
        xr[2*t] = v.x; xr[2*t+1] = v.y;
      }
#pragma unroll
      for (int px = 0; px < 14; ++px) {
        acc[px] = fmaf(xr[px  ], wr[ky*3  ], acc[px]);
        acc[px] = fmaf(xr[px+1], wr[ky*3+1], acc[px]);
        acc[px] = fmaf(xr[px+2], wr[ky*3+2], acc[px]);
      }
    }
  }
  const float s = su2[co], u = su2[32+co];
  float m[7];
#pragma unroll
  for (int p = 0; p < 7; ++p)
    m[p] = fmaxf(acc[2*p]*s + u, acc[2*p+1]*s + u);
#pragma unroll
  for (int p = 0; p < 7; ++p) {
    const float pm = __shfl_xor(m[p], 32);
    m[p] = fmaxf(fmaxf(m[p], pm), 0.f);
  }
  if (cr == 0) {
    float* op = &out[(((size_t)b*32 + co)*56 + band)*56 + xh*28 + w*7];
#pragma unroll
    for (int p = 0; p < 7; ++p) op[p] = m[p];
  }
}

// -------- conv3 (32->64)+BN+ReLU+partial mean: weight prefetch --------------
__global__ __launch_bounds__(256) void conv3(
    const float* __restrict__ h2, const float* __restrict__ wt3,
    const float* __restrict__ su3, float* __restrict__ part)
{
  const int band = blockIdx.x, b = blockIdx.y;
  const int tid = threadIdx.x;
  const int co = tid & 63, w = tid >> 6;
  __shared__ float in_t[32][3][64];
  __shared__ float red[4][64];
  for (int i = tid; i < 32*3*58; i += 256) {
    const int c = i % 58, r = (i / 58) % 3, cc = i / 174;
    const int y = band - 1 + r, gx = c - 1;
    float v = 0.f;
    if (y >= 0 && y < 56 && gx >= 0 && gx < 56)
      v = h2[(((size_t)b*32 + cc)*56 + y)*56 + gx];
    in_t[cc][r][c] = v;
  }
  __syncthreads();
  const int X0 = w * 14;
  float acc[14];
#pragma unroll
  for (int px = 0; px < 14; ++px) acc[px] = 0.f;
  const float* __restrict__ wp = wt3 + co*12;
  float4 nw0 = *(const float4*)(wp);
  float4 nw1 = *(const float4*)(wp + 4);
  float  nw8 = wp[8];
  for (int cc = 0; cc < 32; ++cc) {
    const float4 w0 = nw0, w1 = nw1; const float w8 = nw8;
    if (cc < 31) {
      const float* np = wp + (cc + 1) * 768;
      nw0 = *(const float4*)(np);
      nw1 = *(const float4*)(np + 4);
      nw8 = np[8];
    }
    const float wr[9] = {w0.x, w0.y, w0.z, w0.w, w1.x, w1.y, w1.z, w1.w, w8};
#pragma unroll
    for (int rr = 0; rr < 3; ++rr) {
      float xr[16];
      const float2* rp = (const float2*)&in_t[cc][rr][X0];
#pragma unroll
      for (int t = 0; t < 8; ++t) {
        const float2 v = rp[t];
        xr[2*t] = v.x; xr[2*t+1] = v.y;
      }
#pragma unroll
      for (int px = 0; px < 14; ++px) {
        acc[px] = fmaf(xr[px  ], wr[rr*3  ], acc[px]);
        acc[px] = fmaf(xr[px+1], wr[rr*3+1], acc[px]);
        acc[px] = fmaf(xr[px+2], wr[rr*3+2], acc[px]);
      }
    }
  }
  const float s = su3[co], u = su3[64+co];
  float sum = 0.f;
#pragma unroll
  for (int px = 0; px < 14; ++px)
    sum += fmaxf(acc[px]*s + u, 0.f);
  red[w][co] = sum;
  __syncthreads();
  if (tid < 64)
    part[((size_t)b*64 + co)*56 + band] =
        red[0][co] + red[1][co] + red[2][co] + red[3][co];
}

// ------------- global mean (56 partials) + FC + ReLU ------------------------
__global__ __launch_bounds__(128) void mean_fc(
    const float* __restrict__ part, const float* __restrict__ fw,
    const float* __restrict__ fb, float* __restrict__ out)
{
  const int b = blockIdx.x;
  const int tid = threadIdx.x;
  __shared__ float h3s[64];
  if (tid < 64) {
    float s = 0.f;
    const float* pp = part + ((size_t)b*64 + tid)*56;
#pragma unroll
    for (int i = 0; i < 56; ++i) s += pp[i];
    h3s[tid] = s * (1.0f / 3136.0f);
  }
  __syncthreads();
  float acc = fb[tid];
#pragma unroll
  for (int c = 0; c < 64; ++c)
    acc = fmaf(h3s[c], fw[tid*64 + c], acc);
  out[b*128 + tid] = fmaxf(acc, 0.f);
}

extern "C" void kernel_launch(void* const* d_in, const int* in_sizes, int n_in,
                              void* d_out, int out_size, void* d_ws, size_t ws_size,
                              hipStream_t stream) {
  const float* seq  = (const float*)d_in[0];
  const float* dcos = (const float*)d_in[1];
  const float* dsin = (const float*)d_in[2];
  const float* c1w  = (const float*)d_in[3];
  const float* c1b  = (const float*)d_in[4];
  const float* b1g  = (const float*)d_in[5];
  const float* b1b  = (const float*)d_in[6];
  const float* b1m  = (const float*)d_in[7];
  const float* b1v  = (const float*)d_in[8];
  const float* c2w  = (const float*)d_in[9];
  const float* c2b  = (const float*)d_in[10];
  const float* b2g  = (const float*)d_in[11];
  const float* b2b  = (const float*)d_in[12];
  const float* b2m  = (const float*)d_in[13];
  const float* b2v  = (const float*)d_in[14];
  const float* c3w  = (const float*)d_in[15];
  const float* c3b  = (const float*)d_in[16];
  const float* b3g  = (const float*)d_in[17];
  const float* b3b  = (const float*)d_in[18];
  const float* b3m  = (const float*)d_in[19];
  const float* b3v  = (const float*)d_in[20];
  const float* fw   = (const float*)d_in[21];
  const float* fb   = (const float*)d_in[22];
  float* out = (float*)d_out;

  float* ws   = (float*)d_ws;
  float* Cx   = ws;                   // 1,214,976 (113 rows x 224, 48 imgs)
  float* Sx   = ws + OFF_SX;          // 1,214,976
  float* spec = ws + OFF_SPEC;        // 2,408,448
  float* h1   = ws;                   // 3,211,264 (reuses dead Cx/Sx)
  float* h2   = ws + OFF_SPEC;        // 1,605,632 (reuses dead spec)
  float* wt3  = ws + OFF_WT;
  float* wt2  = ws + OFF_WT2;
  float* wt1  = ws + OFF_WT1;
  float* su3  = ws + OFF_SU3;
  float* su2  = ws + OFF_SU2;
  float* su1  = ws + OFF_SU1;
  float* part = ws + OFF_PART;        // 57,344

  prep<<<24, 256, 0, stream>>>(c1w, c2w, c3w, c1b, c2b, c3b,
                               b1g, b1b, b1m, b1v, b2g, b2b, b2m, b2v,
                               b3g, b3b, b3m, b3v, wt3, wt2, wt1, su3, su2, su1);
  dft1<<<dim3(7, 4, 48), 256, 0, stream>>>(seq, dcos, dsin, Cx, Sx);
  dft2<<<dim3(4, 4, 48), 256, 0, stream>>>(Cx, Sx, dcos, dsin, spec);
  conv1<<<dim3(112, 16), 256, 0, stream>>>(spec, wt1, su1, h1);
  conv2<<<dim3(2, 56, 16), 256, 0, stream>>>(h1, wt2, su2, h2);
  conv3<<<dim3(56, 16), 256, 0, stream>>>(h2, wt3, su3, part);
  mean_fc<<<16, 128, 0, stream>>>(part, fw, fb, out);
}